// Round 1
// baseline (637.433 us; speedup 1.0000x reference)
//
#include <hip/hip_runtime.h>

#define B_N 256
#define T_LEN 1460
#define M_N 16
#define DPTH 8   // prefetch depth (register pipeline)

__device__ __forceinline__ float sigmf(float x) {
    // sigmoid(x) = 1 / (1 + 2^(-x*log2(e)))
    float e = __builtin_amdgcn_exp2f(-1.44269504f * x);
    return __builtin_amdgcn_rcpf(1.0f + e);
}

__global__ __launch_bounds__(64, 1) void shm_scan_kernel(
    const float* __restrict__ xc,    // [B, T, 3]
    const float* __restrict__ lo,    // [B, T, 8, 16]
    float* __restrict__ out)         // [B, T]
{
    const int gid = blockIdx.x * 64 + threadIdx.x;
    const int b = gid >> 4;
    const int m = gid & 15;

    const float* lp = lo + (size_t)b * T_LEN * 128 + m;   // + t*128 + i*16
    const float* xp = xc + (size_t)b * T_LEN * 3;         // + t*3 + c
    float* op = out + (size_t)b * T_LEN;

    // states
    float ss = 0.0f, sf = 1.0f, su = 5.0f, si = 10.0f, sb = 15.0f;

    // register prefetch pipeline
    float pb[DPTH][8];
    float xb[DPTH][3];
#pragma unroll
    for (int j = 0; j < DPTH; ++j) {
#pragma unroll
        for (int i = 0; i < 8; ++i) pb[j][i] = lp[(size_t)j * 128 + i * 16];
#pragma unroll
        for (int c = 0; c < 3; ++c) xb[j][c] = xp[(size_t)j * 3 + c];
    }

    auto step = [&](int t, float raw0, float raw1, float raw2, float raw3,
                    float raw4, float raw5, float raw6, float raw7,
                    float prec, float et, float temp) {
        // dynamic sigmoid-rescaled parameters
        float dd    = 10.0f * sigmf(raw0);
        float f_thr = 10.0f + 50.0f  * sigmf(raw1);
        float sumax = 20.0f + 680.0f * sigmf(raw2);
        float beta  = 1.0f  + 5.0f   * sigmf(raw3);
        float perc  =                  sigmf(raw4);
        float kf    = 1.0f  + 19.0f  * sigmf(raw5);
        float ki    = 1.0f  + 99.0f  * sigmf(raw6);
        float kb    = 10.0f + 990.0f * sigmf(raw7);

        bool frozen = (temp < 0.0f);
        float sm  = frozen ? 0.0f : temp * dd;
        float lpq = frozen ? 0.0f : prec;
        float sn  = frozen ? prec : 0.0f;
        float pwp = 0.8f * sumax;

        // snow bucket
        float qs_out = fminf(ss, sm);
        ss = ss - qs_out + sn;
        float qsp = qs_out + lpq;
        // fast / unsaturated split
        float qf_in = fmaxf(0.0f, qsp - f_thr);
        float qu_in = fminf(qsp, f_thr);
        // fast reservoir
        sf += qf_in;
        float qf_out = sf * __builtin_amdgcn_rcpf(kf);
        sf -= qf_out;
        // unsaturated zone
        float inv_sumax = __builtin_amdgcn_rcpf(sumax);
        float u = su * inv_sumax;
        float psi = __builtin_amdgcn_exp2f(beta * __builtin_amdgcn_logf(u));
        float su_temp = su + qu_in * (1.0f - psi);
        su = fminf(su_temp, sumax);
        float qu_out = qu_in * psi + fmaxf(0.0f, su_temp - sumax);
        float ktheta = (su <= pwp) ? su * inv_sumax : 1.0f;
        float ret = et * 0.9f * ktheta;
        su = fmaxf(0.0f, su - ret);
        // interflow reservoir
        float qi_in = qu_out * perc;
        si += qi_in;
        float qi_out = si * __builtin_amdgcn_rcpf(ki);
        si -= qi_out;
        // baseflow reservoir
        float qb_in = qu_out - qi_in;  // == qu_out * (1 - perc)
        sb += qb_in;
        float qb_out = sb * __builtin_amdgcn_rcpf(kb);
        sb -= qb_out;

        float q = qf_out + qi_out + qb_out;
        // mean over the 16 models of this basin (lanes m=0..15 contiguous)
        q += __shfl_xor(q, 1);
        q += __shfl_xor(q, 2);
        q += __shfl_xor(q, 4);
        q += __shfl_xor(q, 8);
        if (m == 0) op[t] = q * 0.0625f;
    };

    constexpr int T_MAIN = (T_LEN / DPTH) * DPTH;  // 1456

    for (int tb = 0; tb < T_MAIN; tb += DPTH) {
#pragma unroll
        for (int j = 0; j < DPTH; ++j) {
            const int t = tb + j;
            // pull current slot into locals
            float r0 = pb[j][0], r1 = pb[j][1], r2 = pb[j][2], r3 = pb[j][3];
            float r4 = pb[j][4], r5 = pb[j][5], r6 = pb[j][6], r7 = pb[j][7];
            float xprec = xb[j][0], xet = xb[j][1], xtemp = xb[j][2];
            // prefetch t + DPTH into this slot
            if (t + DPTH < T_LEN) {
                const float* lpn = lp + (size_t)(t + DPTH) * 128;
#pragma unroll
                for (int i = 0; i < 8; ++i) pb[j][i] = lpn[i * 16];
                const float* xpn = xp + (size_t)(t + DPTH) * 3;
#pragma unroll
                for (int c = 0; c < 3; ++c) xb[j][c] = xpn[c];
            }
            step(t, r0, r1, r2, r3, r4, r5, r6, r7, xprec, xet, xtemp);
        }
    }
    // tail: t = 1456..1459, slots j = t & 7 already hold their data
#pragma unroll
    for (int j = 0; j < T_LEN - T_MAIN; ++j) {
        const int t = T_MAIN + j;
        step(t, pb[j][0], pb[j][1], pb[j][2], pb[j][3],
                pb[j][4], pb[j][5], pb[j][6], pb[j][7],
                xb[j][0], xb[j][1], xb[j][2]);
    }
}

extern "C" void kernel_launch(void* const* d_in, const int* in_sizes, int n_in,
                              void* d_out, int out_size, void* d_ws, size_t ws_size,
                              hipStream_t stream) {
    const float* xc = (const float*)d_in[0];   // x_conceptual [256,1460,3]
    const float* lo = (const float*)d_in[1];   // lstm_out     [256,1460,128]
    float* out = (float*)d_out;                // [256,1460,1]

    dim3 grid(B_N * M_N / 64);  // 64 blocks
    dim3 block(64);
    shm_scan_kernel<<<grid, block, 0, stream>>>(xc, lo, out);
}

// Round 2
// 325.938 us; speedup vs baseline: 1.9557x; 1.9557x over previous
//
#include <hip/hip_runtime.h>

#define T_LEN 1460
#define CS 10              // timesteps per chunk
#define NCHUNK 146         // 146*10 = 1460 exactly
#define IST 66             // padded i-stride (dwords) in param LDS: kills bank conflicts

__device__ __forceinline__ float sigmf(float x) {
    float e = __builtin_amdgcn_exp2f(-1.44269504f * x);
    return __builtin_amdgcn_rcpf(1.0f + e);
}
__device__ __forceinline__ float rcpf(float x) { return __builtin_amdgcn_rcpf(x); }

__device__ __forceinline__ float lane0f(float x) {
    return __int_as_float(__builtin_amdgcn_readlane(__float_as_int(x), 0));
}

// sum over each 16-lane row via full-rate DPP adds (no DS ops):
// xor1 = quad_perm(1,0,3,2)=0xB1; xor2 = quad_perm(2,3,0,1)=0x4E;
// then row_half_mirror (0x141) and row_mirror (0x140).
__device__ __forceinline__ float row_sum16(float x) {
    x += __int_as_float(__builtin_amdgcn_update_dpp(0, __float_as_int(x), 0xB1, 0xF, 0xF, true));
    x += __int_as_float(__builtin_amdgcn_update_dpp(0, __float_as_int(x), 0x4E, 0xF, 0xF, true));
    x += __int_as_float(__builtin_amdgcn_update_dpp(0, __float_as_int(x), 0x141, 0xF, 0xF, true));
    x += __int_as_float(__builtin_amdgcn_update_dpp(0, __float_as_int(x), 0x140, 0xF, 0xF, true));
    return x;
}

__global__ __launch_bounds__(256, 1) void shm_pc_kernel(
    const float* __restrict__ xc,    // [B, T, 3]
    const float* __restrict__ lo,    // [B, T, 8, 16]
    float* __restrict__ out)         // [B, T]
{
    // params: [buf][tl][param i][chain 0..63], padded stride 66
    __shared__ float pbuf[2][CS][8][IST];      // 42240 B
    // per-(b,t) broadcast values {sn, lpq, et09, -}
    __shared__ float bbuf[2][CS][4][4];        // 1280 B

    const int lane  = threadIdx.x & 63;
    const int wid   = threadIdx.x >> 6;
    const int bbase = blockIdx.x * 4;

    // ---------------- producer constants (per lane, hoisted) ----------------
    // lane covers lstm flat elems f = 2*lane, 2*lane+1 of the 128-float (b,t) record.
    // param index i = f>>4 = lane>>3 (same for both elems); m = f&15.
    const int ip = lane >> 3;
    const float A  = (ip==1)?10.f : (ip==2)?20.f : (ip==3)?1.f :
                     (ip==5)?1.f  : (ip==6)?1.f  : (ip==7)?10.f : 0.f;
    const float Bc = (ip==0)?10.f : (ip==1)?50.f : (ip==2)?680.f : (ip==3)?5.f :
                     (ip==4)?1.f  : (ip==5)?19.f : (ip==6)?99.f  : 990.f;
    const bool drcp = (ip >= 5);   // kf, ki, kb stored as reciprocals
    const bool dsm  = (ip == 0);   // dd stored as sm = tpos*dd
    const int  mm   = (2*lane) & 15;

    auto produce = [&](int cc, int buf) {
        // tasks tau = 0..39 : g = tau/10 (b within block), tl = tau%10
        const int t0 = cc * CS;
        float2 raw[14];
        float xr0[14], xr1[14], xr2[14];
#pragma unroll
        for (int r = 0; r < 14; ++r) {
            const int tau = (wid - 1) + 3 * r;        // wave-uniform
            if (tau < 40) {
                const int g  = tau / CS;
                const int tl = tau - g * CS;
                const size_t rowoff = (size_t)(bbase + g) * T_LEN + (t0 + tl);
                raw[r] = *(const float2*)(lo + rowoff * 128 + 2 * lane);
                if (lane == 0) {
                    const float* xp = xc + rowoff * 3;
                    xr0[r] = xp[0]; xr1[r] = xp[1]; xr2[r] = xp[2];
                }
            }
        }
#pragma unroll
        for (int r = 0; r < 14; ++r) {
            const int tau = (wid - 1) + 3 * r;
            if (tau < 40) {
                const int g  = tau / CS;
                const int tl = tau - g * CS;
                const float prec = lane0f(xr0[r]);
                const float pet  = lane0f(xr1[r]);
                const float temp = lane0f(xr2[r]);
                const bool frozen = (temp < 0.f);
                const float tpos = frozen ? 0.f : temp;
                const float sn   = frozen ? prec : 0.f;
                const float lpq  = frozen ? 0.f : prec;
                const float et09 = 0.9f * pet;

                float s0 = sigmf(raw[r].x);
                float s1 = sigmf(raw[r].y);
                float v0 = fmaf(s0, Bc, A);
                float v1 = fmaf(s1, Bc, A);
                v0 = drcp ? rcpf(v0) : v0;
                v1 = drcp ? rcpf(v1) : v1;
                v0 = dsm ? v0 * tpos : v0;
                v1 = dsm ? v1 * tpos : v1;

                float* dst = &pbuf[buf][tl][ip][g * 16 + mm];
                *(float2*)dst = make_float2(v0, v1);   // 8B-aligned (mm even, IST even)
                if (lane == 0)
                    *(float4*)&bbuf[buf][tl][g][0] = make_float4(sn, lpq, et09, 0.f);
            }
        }
    };

    // ---------------- consumer state ----------------
    const int g = lane >> 4, m = lane & 15;
    float ss = 0.f, sf = 1.f, su = 5.f, si = 10.f, sb = 15.f;
    float* op = out + (size_t)(bbase + g) * T_LEN;

    // prologue: fill chunk 0
    if (wid != 0) produce(0, 0);
    __syncthreads();

    for (int c = 0; c < NCHUNK; ++c) {
        if (wid == 0) {
            const int buf = c & 1;
#pragma unroll
            for (int tl = 0; tl < CS; ++tl) {
                const float* rec = &pbuf[buf][tl][0][lane];
                const float sm    = rec[0 * IST];
                const float f_thr = rec[1 * IST];
                const float sumax = rec[2 * IST];
                const float beta  = rec[3 * IST];
                const float perc  = rec[4 * IST];
                const float rkf   = rec[5 * IST];
                const float rki   = rec[6 * IST];
                const float rkb   = rec[7 * IST];
                const float4 bx = *(const float4*)&bbuf[buf][tl][g][0];
                const float sn = bx.x, lpq = bx.y, et09 = bx.z;

                // snow bucket
                float qs_out = fminf(ss, sm);
                ss = ss - qs_out + sn;
                float qsp = qs_out + lpq;
                // split
                float qf_in = fmaxf(0.f, qsp - f_thr);
                float qu_in = fminf(qsp, f_thr);
                // fast reservoir
                sf += qf_in;
                float qf_out = sf * rkf;
                sf -= qf_out;
                // unsaturated zone
                float inv_sumax = rcpf(sumax);
                float u = su * inv_sumax;
                float psi = __builtin_amdgcn_exp2f(beta * __builtin_amdgcn_logf(u));
                float su_temp = fmaf(qu_in, 1.f - psi, su);
                su = fminf(su_temp, sumax);
                float ovf = fmaxf(0.f, su_temp - sumax);
                float qu_out = fmaf(qu_in, psi, ovf);
                float pwp = 0.8f * sumax;
                float ktheta = (su <= pwp) ? su * inv_sumax : 1.f;
                float ret = et09 * ktheta;
                su = fmaxf(0.f, su - ret);
                // interflow
                float qi_in = qu_out * perc;
                si += qi_in;
                float qi_out = si * rki;
                si -= qi_out;
                // baseflow
                float qb_in = qu_out - qi_in;
                sb += qb_in;
                float qb_out = sb * rkb;
                sb -= qb_out;

                float q = row_sum16(qf_out + qi_out + qb_out) * 0.0625f;
                if (m == 0) op[c * CS + tl] = q;
            }
        } else if (c + 1 < NCHUNK) {
            produce(c + 1, (c + 1) & 1);
        }
        __syncthreads();
    }
}

extern "C" void kernel_launch(void* const* d_in, const int* in_sizes, int n_in,
                              void* d_out, int out_size, void* d_ws, size_t ws_size,
                              hipStream_t stream) {
    const float* xc = (const float*)d_in[0];   // [256,1460,3]
    const float* lo = (const float*)d_in[1];   // [256,1460,128]
    float* out = (float*)d_out;                // [256,1460,1]

    shm_pc_kernel<<<dim3(64), dim3(256), 0, stream>>>(xc, lo, out);
}